// Round 1
// baseline (263.873 us; speedup 1.0000x reference)
//
#include <hip/hip_runtime.h>

#define DEV __device__ __forceinline__

typedef _Float16 f16x8 __attribute__((ext_vector_type(8)));
typedef float f32x4 __attribute__((ext_vector_type(4)));
typedef unsigned short u16;
typedef unsigned int u32;

DEV u16 f2h(float f) { _Float16 h = (_Float16)f; return __builtin_bit_cast(u16, h); }
DEV float h2f(u16 u) { return (float)__builtin_bit_cast(_Float16, u); }

DEV void gl_lds16(const void* g, void* l) {
  __builtin_amdgcn_global_load_lds((__attribute__((address_space(1))) void*)(g),
                                   (__attribute__((address_space(3))) void*)(l), 16, 0, 0);
}

#define MFMA16(a, b, c) __builtin_amdgcn_mfma_f32_16x16x32_f16(a, b, c, 0, 0, 0)

DEV f16x8 lds_frag(const u16* p) { return *reinterpret_cast<const f16x8*>(p); }

// ---------------- K1: LayerNorm (f32 in, f16 out) ----------------
__global__ __launch_bounds__(256) void k_ln(const float* __restrict__ x,
                                            const float* __restrict__ g,
                                            const float* __restrict__ b,
                                            u16* __restrict__ xn) {
  const int row = blockIdx.x;
  const int t = threadIdx.x;
  const float4 v = reinterpret_cast<const float4*>(x + (size_t)row * 1024)[t];
  float s = v.x + v.y + v.z + v.w;
  float s2 = v.x * v.x + v.y * v.y + v.z * v.z + v.w * v.w;
#pragma unroll
  for (int m = 1; m < 64; m <<= 1) { s += __shfl_xor(s, m); s2 += __shfl_xor(s2, m); }
  __shared__ float ls[8];
  const int wid = t >> 6, lane = t & 63;
  if (lane == 0) { ls[wid] = s; ls[4 + wid] = s2; }
  __syncthreads();
  s = ls[0] + ls[1] + ls[2] + ls[3];
  s2 = ls[4] + ls[5] + ls[6] + ls[7];
  const float mu = s * (1.0f / 1024.0f);
  const float rs = rsqrtf(s2 * (1.0f / 1024.0f) - mu * mu + 1e-5f);
  const float4 gv = reinterpret_cast<const float4*>(g)[t];
  const float4 bv = reinterpret_cast<const float4*>(b)[t];
  ushort4 o;
  o.x = f2h((v.x - mu) * rs * gv.x + bv.x);
  o.y = f2h((v.y - mu) * rs * gv.y + bv.y);
  o.z = f2h((v.z - mu) * rs * gv.z + bv.z);
  o.w = f2h((v.w - mu) * rs * gv.w + bv.w);
  reinterpret_cast<ushort4*>(xn + (size_t)row * 1024)[t] = o;
}

// ---------------- K2: weight convert f32 -> f16 (Wq|Wk|Wv then Wo) ----------------
__global__ __launch_bounds__(256) void k_cvt(const float* __restrict__ wq,
                                             const float* __restrict__ wk,
                                             const float* __restrict__ wv,
                                             const float* __restrict__ wo,
                                             u16* __restrict__ out) {
  const int i = blockIdx.x * 256 + threadIdx.x;  // float4 index, 1M total
  const int seg = i >> 18;                       // 256K float4 per matrix
  const float* src = seg == 0 ? wq : seg == 1 ? wk : seg == 2 ? wv : wo;
  const float4 v = reinterpret_cast<const float4*>(src)[i & 0x3FFFF];
  ushort4 o;
  o.x = f2h(v.x); o.y = f2h(v.y); o.z = f2h(v.z); o.w = f2h(v.w);
  reinterpret_cast<ushort4*>(out)[i] = o;
}

// ---------------- GEMM-BT core: C(128x128) = A(MxK) * B(NxK)^T ----------------
template <int KD>
DEV void gemm_bt_acc(const u16* __restrict__ A, const u16* __restrict__ B,
                     int m0, int n0, u16* As, u16* Bs, f32x4 acc[4][4]) {
  const int t = threadIdx.x;
  const int wid = t >> 6, lane = t & 63;
  const int wr = wid >> 1, wc = wid & 1;
#pragma unroll
  for (int i = 0; i < 4; ++i)
#pragma unroll
    for (int j = 0; j < 4; ++j) acc[i][j] = (f32x4){0.f, 0.f, 0.f, 0.f};
  const int lrow = t >> 2;        // 0..63
  const int lcol = (t & 3) * 8;   // 0,8,16,24
  const int fr = lane & 15, fk = (lane >> 4) * 8;
  for (int k0 = 0; k0 < KD; k0 += 32) {
    __syncthreads();
    gl_lds16(A + (size_t)(m0 + lrow) * KD + k0 + lcol, As + wid * 512);
    gl_lds16(A + (size_t)(m0 + 64 + lrow) * KD + k0 + lcol, As + 2048 + wid * 512);
    gl_lds16(B + (size_t)(n0 + lrow) * KD + k0 + lcol, Bs + wid * 512);
    gl_lds16(B + (size_t)(n0 + 64 + lrow) * KD + k0 + lcol, Bs + 2048 + wid * 512);
    __syncthreads();
    f16x8 af[4], bfr[4];
#pragma unroll
    for (int mf = 0; mf < 4; ++mf) af[mf] = lds_frag(As + (wr * 64 + mf * 16 + fr) * 32 + fk);
#pragma unroll
    for (int nf = 0; nf < 4; ++nf) bfr[nf] = lds_frag(Bs + (wc * 64 + nf * 16 + fr) * 32 + fk);
#pragma unroll
    for (int mf = 0; mf < 4; ++mf)
#pragma unroll
      for (int nf = 0; nf < 4; ++nf) acc[mf][nf] = MFMA16(af[mf], bfr[nf], acc[mf][nf]);
  }
}

// ---------------- K3: QKV projection GEMM, scatter epilogue ----------------
__global__ __launch_bounds__(256) void k_qkv(const u16* __restrict__ xn, const u16* __restrict__ wcat,
                                             const float* __restrict__ bq, const float* __restrict__ bk,
                                             const float* __restrict__ bv,
                                             u16* __restrict__ Qb, u16* __restrict__ Kb,
                                             u16* __restrict__ VTb) {
  __shared__ u16 As[128 * 32], Bs[128 * 32];
  f32x4 acc[4][4];
  const int m0 = blockIdx.x * 128, n0 = blockIdx.y * 128;
  gemm_bt_acc<1024>(xn, wcat, m0, n0, As, Bs, acc);
  const int t = threadIdx.x;
  const int wid = t >> 6, lane = t & 63;
  const int wr = wid >> 1, wc = wid & 1;
  const int fr = lane & 15, fg = (lane >> 4) * 4;
#pragma unroll
  for (int nf = 0; nf < 4; ++nf) {
    const int n = n0 + wc * 64 + nf * 16 + fr;
    const int which = n >> 10, f = n & 1023, h = f >> 6, dk = f & 63;
    const float biasv = which == 0 ? bq[f] : which == 1 ? bk[f] : bv[f];
#pragma unroll
    for (int mf = 0; mf < 4; ++mf) {
#pragma unroll
      for (int r = 0; r < 4; ++r) {
        const int m = m0 + wr * 64 + mf * 16 + fg + r;
        const int bb = m >> 10, tt = m & 1023;
        const int bh = bb * 16 + h;
        const float v = acc[mf][nf][r] + biasv;
        if (which == 0) {
          Qb[((size_t)bh * 1024 + tt) * 64 + dk] = f2h(v * 0.125f);  // fold 1/sqrt(DK)
        } else if (which == 1) {
          Kb[((size_t)bh * 1024 + tt) * 64 + dk] = f2h(v);
        } else {
          VTb[((size_t)bh * 64 + dk) * 1024 + tt] = f2h(v);          // V pre-transposed
        }
      }
    }
  }
}

// ---------------- K4: relative-position bias GEMM (per q) ----------------
// Bias[bh, q, k] = Q[bh,q,:] . pos_k[q,k,:]   (Q already scaled by 0.125)
__global__ __launch_bounds__(256) void k_bias(const u16* __restrict__ Qb,
                                              const float* __restrict__ pos_k,
                                              u16* __restrict__ biasb) {
  const int q = blockIdx.x;
  __shared__ u16 Qs[64 * 64];   // (bh, d)
  __shared__ u16 Ps[256 * 64];  // (k, d) chunk as f16
  const int t = threadIdx.x;
  const int wid = t >> 6, lane = t & 63;
  const int r8 = t >> 3, c8 = (t & 7) * 8;
  gl_lds16(Qb + ((size_t)r8 * 1024 + q) * 64 + c8, Qs + wid * 512);
  gl_lds16(Qb + ((size_t)(32 + r8) * 1024 + q) * 64 + c8, Qs + 2048 + wid * 512);
  __syncthreads();
  const int fr = lane & 15, fk8 = (lane >> 4) * 8, fg = (lane >> 4) * 4;
  f16x8 qa[4][2];
#pragma unroll
  for (int mf = 0; mf < 4; ++mf)
#pragma unroll
    for (int ks = 0; ks < 2; ++ks)
      qa[mf][ks] = lds_frag(Qs + (mf * 16 + fr) * 64 + ks * 32 + fk8);
  const float4* src = reinterpret_cast<const float4*>(pos_k + (size_t)q * 65536);
  for (int c = 0; c < 4; ++c) {
    __syncthreads();
#pragma unroll
    for (int j = 0; j < 16; ++j) {
      const int g = j * 256 + t;
      const float4 v = src[c * 4096 + g];
      ushort4 o;
      o.x = f2h(v.x); o.y = f2h(v.y); o.z = f2h(v.z); o.w = f2h(v.w);
      *reinterpret_cast<ushort4*>(Ps + g * 4) = o;
    }
    __syncthreads();
    f32x4 acc[4][4];
#pragma unroll
    for (int nf = 0; nf < 4; ++nf) {
      f16x8 pb0 = lds_frag(Ps + (wid * 64 + nf * 16 + fr) * 64 + fk8);
      f16x8 pb1 = lds_frag(Ps + (wid * 64 + nf * 16 + fr) * 64 + 32 + fk8);
#pragma unroll
      for (int mf = 0; mf < 4; ++mf) {
        acc[mf][nf] = (f32x4){0.f, 0.f, 0.f, 0.f};
        acc[mf][nf] = MFMA16(qa[mf][0], pb0, acc[mf][nf]);
        acc[mf][nf] = MFMA16(qa[mf][1], pb1, acc[mf][nf]);
      }
    }
#pragma unroll
    for (int mf = 0; mf < 4; ++mf)
#pragma unroll
      for (int nf = 0; nf < 4; ++nf)
#pragma unroll
        for (int r = 0; r < 4; ++r) {
          const int bh = mf * 16 + fg + r;
          const int k = c * 256 + wid * 64 + nf * 16 + fr;
          biasb[(size_t)bh * 1048576 + (size_t)q * 1024 + k] = f2h(acc[mf][nf][r]);
        }
  }
}

// ---------------- K5: flash attention with precomputed bias ----------------
__global__ __launch_bounds__(256) void k_attn(const u16* __restrict__ Qb, const u16* __restrict__ Kb,
                                              const u16* __restrict__ VTb, const u16* __restrict__ biasb,
                                              u16* __restrict__ Ob) {
  const int qt = blockIdx.x, bh = blockIdx.y;
  const int q0 = qt * 64;
  __shared__ u16 Qs[64 * 64], Ks[64 * 64], Vs[64 * 64], Bts[64 * 64];
  __shared__ u16 Psm[4][16 * 64];
  const int t = threadIdx.x;
  const int wid = t >> 6, lane = t & 63;
  const int r8 = t >> 3, c8 = (t & 7) * 8;
  gl_lds16(Qb + ((size_t)bh * 1024 + q0 + r8) * 64 + c8, Qs + wid * 512);
  gl_lds16(Qb + ((size_t)bh * 1024 + q0 + 32 + r8) * 64 + c8, Qs + 2048 + wid * 512);
  __syncthreads();
  const int fr = lane & 15, fk8 = (lane >> 4) * 8, fg = (lane >> 4) * 4;
  f16x8 qa0 = lds_frag(Qs + (wid * 16 + fr) * 64 + fk8);
  f16x8 qa1 = lds_frag(Qs + (wid * 16 + fr) * 64 + 32 + fk8);
  float m_r[4], l_r[4];
  f32x4 oacc[4];
#pragma unroll
  for (int r = 0; r < 4; ++r) { m_r[r] = -1e30f; l_r[r] = 0.f; }
#pragma unroll
  for (int d = 0; d < 4; ++d) oacc[d] = (f32x4){0.f, 0.f, 0.f, 0.f};

  for (int kt = 0; kt < 16; ++kt) {
    const int k0 = kt * 64;
    __syncthreads();
    gl_lds16(Kb + ((size_t)bh * 1024 + k0 + r8) * 64 + c8, Ks + wid * 512);
    gl_lds16(Kb + ((size_t)bh * 1024 + k0 + 32 + r8) * 64 + c8, Ks + 2048 + wid * 512);
    gl_lds16(VTb + ((size_t)bh * 64 + r8) * 1024 + k0 + c8, Vs + wid * 512);
    gl_lds16(VTb + ((size_t)bh * 64 + 32 + r8) * 1024 + k0 + c8, Vs + 2048 + wid * 512);
    gl_lds16(biasb + (size_t)bh * 1048576 + (size_t)(q0 + r8) * 1024 + k0 + c8, Bts + wid * 512);
    gl_lds16(biasb + (size_t)bh * 1048576 + (size_t)(q0 + 32 + r8) * 1024 + k0 + c8,
             Bts + 2048 + wid * 512);
    __syncthreads();
    // S = bias + Q K^T  (bias as MFMA C-initializer)
    f32x4 s[4];
#pragma unroll
    for (int nf = 0; nf < 4; ++nf) {
      f32x4 c0;
#pragma unroll
      for (int r = 0; r < 4; ++r) c0[r] = h2f(Bts[(wid * 16 + fg + r) * 64 + nf * 16 + fr]);
      f16x8 kf0 = lds_frag(Ks + (nf * 16 + fr) * 64 + fk8);
      f16x8 kf1 = lds_frag(Ks + (nf * 16 + fr) * 64 + 32 + fk8);
      c0 = MFMA16(qa0, kf0, c0);
      c0 = MFMA16(qa1, kf1, c0);
      s[nf] = c0;
    }
    // online softmax: row = one 16-lane group (rows fg..fg+3 per reg)
    float scale_old[4], psum[4];
#pragma unroll
    for (int r = 0; r < 4; ++r) {
      float v = fmaxf(fmaxf(s[0][r], s[1][r]), fmaxf(s[2][r], s[3][r]));
      v = fmaxf(v, __shfl_xor(v, 1));
      v = fmaxf(v, __shfl_xor(v, 2));
      v = fmaxf(v, __shfl_xor(v, 4));
      v = fmaxf(v, __shfl_xor(v, 8));
      const float mn = fmaxf(m_r[r], v);
      scale_old[r] = __expf(m_r[r] - mn);
      m_r[r] = mn;
      psum[r] = 0.f;
    }
#pragma unroll
    for (int nf = 0; nf < 4; ++nf) {
#pragma unroll
      for (int r = 0; r < 4; ++r) {
        const float p = __expf(s[nf][r] - m_r[r]);
        psum[r] += p;
        Psm[wid][(fg + r) * 64 + nf * 16 + fr] = f2h(p);
      }
    }
#pragma unroll
    for (int r = 0; r < 4; ++r) {
      float v = psum[r];
      v += __shfl_xor(v, 1); v += __shfl_xor(v, 2);
      v += __shfl_xor(v, 4); v += __shfl_xor(v, 8);
      l_r[r] = l_r[r] * scale_old[r] + v;
    }
#pragma unroll
    for (int d = 0; d < 4; ++d)
#pragma unroll
      for (int r = 0; r < 4; ++r) oacc[d][r] *= scale_old[r];
    // PV: A = P (wave-local LDS), B = V^T tile
    f16x8 pa0 = lds_frag(&Psm[wid][fr * 64 + fk8]);
    f16x8 pa1 = lds_frag(&Psm[wid][fr * 64 + 32 + fk8]);
#pragma unroll
    for (int d = 0; d < 4; ++d) {
      f16x8 vf0 = lds_frag(Vs + (d * 16 + fr) * 64 + fk8);
      f16x8 vf1 = lds_frag(Vs + (d * 16 + fr) * 64 + 32 + fk8);
      oacc[d] = MFMA16(pa0, vf0, oacc[d]);
      oacc[d] = MFMA16(pa1, vf1, oacc[d]);
    }
  }
  const int b_ = bh >> 4, h = bh & 15;
#pragma unroll
  for (int r = 0; r < 4; ++r) {
    const float inv = 1.0f / l_r[r];
    const int tq = q0 + wid * 16 + fg + r;
#pragma unroll
    for (int d = 0; d < 4; ++d)
      Ob[((size_t)b_ * 1024 + tq) * 1024 + h * 64 + d * 16 + fr] = f2h(oacc[d][r] * inv);
  }
}

// ---------------- K6: output GEMM ----------------
__global__ __launch_bounds__(256) void k_out(const u16* __restrict__ Ob, const u16* __restrict__ wo,
                                             const float* __restrict__ bo, float* __restrict__ out) {
  __shared__ u16 As[128 * 32], Bs[128 * 32];
  f32x4 acc[4][4];
  const int m0 = blockIdx.x * 128, n0 = blockIdx.y * 128;
  gemm_bt_acc<1024>(Ob, wo, m0, n0, As, Bs, acc);
  const int t = threadIdx.x;
  const int wid = t >> 6, lane = t & 63;
  const int wr = wid >> 1, wc = wid & 1;
  const int fr = lane & 15, fg = (lane >> 4) * 4;
#pragma unroll
  for (int nf = 0; nf < 4; ++nf) {
    const int n = n0 + wc * 64 + nf * 16 + fr;
    const float biasv = bo[n];
#pragma unroll
    for (int mf = 0; mf < 4; ++mf)
#pragma unroll
      for (int r = 0; r < 4; ++r) {
        const int m = m0 + wr * 64 + mf * 16 + fg + r;
        out[(size_t)m * 1024 + n] = acc[mf][nf][r] + biasv;
      }
  }
}

extern "C" void kernel_launch(void* const* d_in, const int* in_sizes, int n_in,
                              void* d_out, int out_size, void* d_ws, size_t ws_size,
                              hipStream_t stream) {
  (void)in_sizes; (void)n_in; (void)out_size; (void)ws_size;
  const float* x     = (const float*)d_in[0];
  const float* pos_k = (const float*)d_in[1];
  const float* ln_g  = (const float*)d_in[2];
  const float* ln_b  = (const float*)d_in[3];
  const float* Wq    = (const float*)d_in[4];
  const float* bq    = (const float*)d_in[5];
  const float* Wk    = (const float*)d_in[6];
  const float* bk    = (const float*)d_in[7];
  const float* Wv    = (const float*)d_in[8];
  const float* bv    = (const float*)d_in[9];
  const float* Wo    = (const float*)d_in[10];
  const float* bo    = (const float*)d_in[11];
  float* out = (float*)d_out;
  char* ws = (char*)d_ws;
  u16* xn    = (u16*)(ws);                      // 8 MB
  u16* wcat  = (u16*)(ws + (8u << 20));         // 6 MB (Wq|Wk|Wv), then Wo 2 MB
  u16* wo_h  = (u16*)(ws + (14u << 20));
  u16* Qb    = (u16*)(ws + (16u << 20));        // 8 MB (bh, t, dk), scaled by 0.125
  u16* Kb    = (u16*)(ws + (24u << 20));        // 8 MB (bh, t, dk)
  u16* VTb   = (u16*)(ws + (32u << 20));        // 8 MB (bh, dk, t)
  u16* Ob    = (u16*)(ws + (40u << 20));        // 8 MB (b, t, h, dk)
  u16* biasb = (u16*)(ws + (48u << 20));        // 128 MB (bh, q, k)

  k_ln<<<4096, 256, 0, stream>>>(x, ln_g, ln_b, xn);
  k_cvt<<<4096, 256, 0, stream>>>(Wq, Wk, Wv, Wo, wcat);
  k_qkv<<<dim3(32, 24), 256, 0, stream>>>(xn, wcat, bq, bk, bv, Qb, Kb, VTb);
  k_bias<<<1024, 256, 0, stream>>>(Qb, pos_k, biasb);
  k_attn<<<dim3(16, 64), 256, 0, stream>>>(Qb, Kb, VTb, biasb, Ob);
  k_out<<<dim3(32, 8), 256, 0, stream>>>(Ob, wo_h, bo, out);
}